// Round 8
// baseline (42.476 us; speedup 1.0000x reference)
//
#include <hip/hip_runtime.h>

#define K_NEIGH 16
#define IN_DIM 128
#define OUT_DIM 128
#define TWO_D 256

#define BM 32          // nodes per block
#define LSTR 264       // ushort elems per LDS comb row (528 B); == 132 floats for out staging

typedef __attribute__((ext_vector_type(8))) short bf16x8;
typedef __attribute__((ext_vector_type(4))) unsigned short u16x4;
typedef __attribute__((ext_vector_type(4))) float f32x4;
typedef __attribute__((ext_vector_type(2))) float f32x2;

__device__ __forceinline__ unsigned short f2bf(float x) {
    union { float f; unsigned u; } v; v.f = x;
    unsigned r = v.u + 0x7fffu + ((v.u >> 16) & 1u);   // RNE
    return (unsigned short)(r >> 16);
}

// ---- one prep kernel: blocks [0,16) build W-fragments; blocks [16,..) build fp8 table ----
// wfrag layout (verified R2-R6):
// frag[((nt*8 + ks)*64 + lane)*8 + j] = bf16( W[nt*16 + (lane&15)][ks*32 + (lane>>4)*8 + j] )
__global__ void prep_all(const float* __restrict__ W, const float* __restrict__ embs,
                         unsigned short* __restrict__ wfrag, unsigned* __restrict__ f8tab,
                         int total_ints) {
    const int b = blockIdx.x;
    if (b < 16) {
        const int t = b * 256 + threadIdx.x;          // 0..4095
        const int lane = t & 63;
        const int ks = (t >> 6) & 7;
        const int nt = t >> 9;
        const int n  = nt * 16 + (lane & 15);
        const int k0 = ks * 32 + (lane >> 4) * 8;
        const float* src = W + (size_t)n * TWO_D + k0;
        const float4 a = *reinterpret_cast<const float4*>(src);
        const float4 c = *reinterpret_cast<const float4*>(src + 4);
        ushort4 lo = { f2bf(a.x), f2bf(a.y), f2bf(a.z), f2bf(a.w) };
        ushort4 hi = { f2bf(c.x), f2bf(c.y), f2bf(c.z), f2bf(c.w) };
        unsigned short* dst = wfrag + (size_t)t * 8;
        *reinterpret_cast<ushort4*>(dst)     = lo;
        *reinterpret_cast<ushort4*>(dst + 4) = hi;
    } else {
        // fp8 e4m3 table: one int = 4 fp8 elems, from one float4 of embs
        int i = (b - 16) * 256 + threadIdx.x;
        const int stride = (gridDim.x - 16) * 256;
        for (; i < total_ints; i += stride) {
            const float4 v = reinterpret_cast<const float4*>(embs)[i];
            int p = 0;
            p = __builtin_amdgcn_cvt_pk_fp8_f32(v.x, v.y, p, false);
            p = __builtin_amdgcn_cvt_pk_fp8_f32(v.z, v.w, p, true);
            f8tab[i] = (unsigned)p;
        }
    }
}

template <int USE_F8>
__global__ __launch_bounds__(512, 8)
void sage_fused(const int* __restrict__ nodes,
                const float* __restrict__ embs,
                const unsigned* __restrict__ f8tab,
                const int* __restrict__ neigh,
                const unsigned short* __restrict__ wfrag,
                float* __restrict__ out,
                int n_nodes)
{
    __shared__ unsigned short comb[BM * LSTR];   // bf16 combined; reused as fp32 out staging
    __shared__ int sidx[BM];
    __shared__ int nb[BM * K_NEIGH];

    const int tid = threadIdx.x;
    const int block_n0 = blockIdx.x * BM;
    const int nvalid = min(BM, n_nodes - block_n0);

    // ---------- Phase 0: stage indices (512 threads == BM*K_NEIGH exactly) ----------
    if (tid < BM)
        sidx[tid] = (tid < nvalid) ? nodes[block_n0 + tid] : 0;
    nb[tid] = (tid < nvalid * K_NEIGH) ? neigh[(size_t)block_n0 * K_NEIGH + tid] : 0;
    __syncthreads();

    // ---------- Phase 1: gather. 32 lanes/node, 2 passes; self fp32 first, then 16 fp8 ----
    {
        const int l = tid & 31;           // elem range [4l, 4l+4)
        #pragma unroll
        for (int s = 0; s < 2; ++s) {
            const int nloc = s * 16 + (tid >> 5);   // 0..31
            unsigned short* row = &comb[nloc * LSTR];
            if (nloc < nvalid) {
                const int* nptr = &nb[nloc * K_NEIGH];
                // self: fp32 direct -> bf16 cols [0,128)  (issued first: L3 latency)
                const float4 sv = *reinterpret_cast<const float4*>(
                    embs + (size_t)sidx[nloc] * IN_DIM + 4 * l);

                float ax[4] = {0.f, 0.f, 0.f, 0.f};
                if (USE_F8) {
                    unsigned v[K_NEIGH];
                    #pragma unroll
                    for (int k = 0; k < K_NEIGH; ++k)
                        v[k] = f8tab[(size_t)nptr[k] * (IN_DIM / 4) + l];
                    #pragma unroll
                    for (int k = 0; k < K_NEIGH; ++k) {
                        const f32x2 lo = __builtin_amdgcn_cvt_pk_f32_fp8((int)v[k], false);
                        const f32x2 hi = __builtin_amdgcn_cvt_pk_f32_fp8((int)v[k], true);
                        ax[0] += lo[0]; ax[1] += lo[1]; ax[2] += hi[0]; ax[3] += hi[1];
                    }
                } else {
                    #pragma unroll
                    for (int b2 = 0; b2 < 2; ++b2) {
                        float4 v[8];
                        #pragma unroll
                        for (int k = 0; k < 8; ++k)
                            v[k] = *reinterpret_cast<const float4*>(
                                embs + (size_t)nptr[b2 * 8 + k] * IN_DIM + 4 * l);
                        #pragma unroll
                        for (int k = 0; k < 8; ++k) {
                            ax[0] += v[k].x; ax[1] += v[k].y; ax[2] += v[k].z; ax[3] += v[k].w;
                        }
                    }
                }
                ushort4 t4 = { f2bf(sv.x), f2bf(sv.y), f2bf(sv.z), f2bf(sv.w) };
                *reinterpret_cast<ushort4*>(row + 4 * l) = t4;
                u16x4 m4;
                #pragma unroll
                for (int j = 0; j < 4; ++j) m4[j] = f2bf(ax[j] * 0.0625f);
                *reinterpret_cast<u16x4*>(row + IN_DIM + 4 * l) = m4;
            } else {
                u16x4 z = { 0, 0, 0, 0 };
                *reinterpret_cast<u16x4*>(row + 4 * l) = z;
                *reinterpret_cast<u16x4*>(row + IN_DIM + 4 * l) = z;
            }
        }
    }
    __syncthreads();

    // ---------- Phase 2: MFMA GEMM — 8 waves; wave w: m-tile = w&1, n-tiles {w>>1, (w>>1)+4} --
    const int wave = tid >> 6;            // 0..7
    const int lane = tid & 63;
    const int row16 = lane & 15;
    const int hi    = lane >> 4;          // 0..3 -> k-base hi*8
    const int mt = wave & 1;
    const int nq0 = wave >> 1;            // n-tiles nq0 and nq0+4

    f32x4 acc0 = {0,0,0,0}, acc1 = {0,0,0,0};
    {
        const unsigned short* arow = &comb[(mt * 16 + row16) * LSTR + hi * 8];
        const unsigned short* bb0 = wfrag + ((size_t)nq0 * 8 * 64 + (size_t)lane) * 8;
        const unsigned short* bb1 = wfrag + ((size_t)(nq0 + 4) * 8 * 64 + (size_t)lane) * 8;
        #pragma unroll
        for (int ks = 0; ks < 8; ++ks) {
            const bf16x8 a  = *reinterpret_cast<const bf16x8*>(arow + ks * 32);
            const bf16x8 b0 = *reinterpret_cast<const bf16x8*>(bb0 + (size_t)ks * 64 * 8);
            const bf16x8 b1 = *reinterpret_cast<const bf16x8*>(bb1 + (size_t)ks * 64 * 8);
            acc0 = __builtin_amdgcn_mfma_f32_16x16x32_bf16(a, b0, acc0, 0, 0, 0);
            acc1 = __builtin_amdgcn_mfma_f32_16x16x32_bf16(a, b1, acc1, 0, 0, 0);
        }
    }
    __syncthreads();   // comb A-reads done

    // ---------- Phase 3: stage relu(acc) in LDS [32][132], nontemporal coalesced stores ----
    {
        float* otile = reinterpret_cast<float*>(comb);
        #pragma unroll
        for (int r = 0; r < 4; ++r) {
            const int mrow = mt * 16 + hi * 4 + r;
            otile[mrow * 132 + nq0 * 16 + row16]       = fmaxf(acc0[r], 0.f);
            otile[mrow * 132 + (nq0 + 4) * 16 + row16] = fmaxf(acc1[r], 0.f);
        }
        __syncthreads();

        const int rrow = tid >> 4;        // 0..31
        const int seg  = tid & 15;        // 8 floats each
        if (rrow < nvalid) {
            const f32x4* src = reinterpret_cast<const f32x4*>(otile + rrow * 132 + seg * 8);
            f32x4* dst = reinterpret_cast<f32x4*>(
                out + (size_t)(block_n0 + rrow) * OUT_DIM + seg * 8);
            __builtin_nontemporal_store(src[0], dst);
            __builtin_nontemporal_store(src[1], dst + 1);
        }
    }
}

extern "C" void kernel_launch(void* const* d_in, const int* in_sizes, int n_in,
                              void* d_out, int out_size, void* d_ws, size_t ws_size,
                              hipStream_t stream) {
    const int*   nodes = (const int*)d_in[0];
    const float* embs  = (const float*)d_in[1];
    const int*   neigh = (const int*)d_in[2];
    const float* W     = (const float*)d_in[3];
    float* out = (float*)d_out;

    const int n_nodes = in_sizes[0];                       // 50000
    const int n_unique = in_sizes[1] / IN_DIM;             // 100000
    const size_t f8tab_bytes = (size_t)n_unique * IN_DIM;  // 12.8 MB (1 B/elem)
    const size_t wfrag_bytes = 8 * 8 * 64 * 8 * 2;         // 64 KiB
    const bool use_f8 = ws_size >= f8tab_bytes + wfrag_bytes;

    unsigned char* base = (unsigned char*)d_ws;
    unsigned* f8tab = (unsigned*)base;
    unsigned short* wfrag = (unsigned short*)(use_f8 ? base + f8tab_bytes : base);

    const int grid = (n_nodes + BM - 1) / BM;              // 1563

    if (use_f8) {
        const int total_ints = (int)(f8tab_bytes / 4);     // 3.2M
        prep_all<<<16 + 2048, 256, 0, stream>>>(W, embs, wfrag, f8tab, total_ints);
        sage_fused<1><<<grid, 512, 0, stream>>>(nodes, embs, f8tab, neigh, wfrag, out, n_nodes);
    } else {
        prep_all<<<16, 256, 0, stream>>>(W, embs, wfrag, f8tab, 0);
        sage_fused<0><<<grid, 512, 0, stream>>>(nodes, embs, f8tab, neigh, wfrag, out, n_nodes);
    }
}

// Round 9
// 40.417 us; speedup vs baseline: 1.0509x; 1.0509x over previous
//
#include <hip/hip_runtime.h>

#define K_NEIGH 16
#define IN_DIM 128
#define OUT_DIM 128
#define TWO_D 256

#define BM 16          // nodes per block (50000 % 16 == 0 -> no tail)
#define LSTR 264       // ushort elems per LDS comb row (528 B); == 132 floats for out staging

typedef __attribute__((ext_vector_type(8))) short bf16x8;
typedef __attribute__((ext_vector_type(4))) unsigned short u16x4;
typedef __attribute__((ext_vector_type(4))) float f32x4;
typedef __attribute__((ext_vector_type(2))) float f32x2;

__device__ __forceinline__ unsigned short f2bf(float x) {
    union { float f; unsigned u; } v; v.f = x;
    unsigned r = v.u + 0x7fffu + ((v.u >> 16) & 1u);   // RNE
    return (unsigned short)(r >> 16);
}

// ---- one prep kernel: blocks [0,16) build W-fragments; blocks [16,..) build fp8 table ----
// wfrag layout (verified R2-R6):
// frag[((nt*8 + ks)*64 + lane)*8 + j] = bf16( W[nt*16 + (lane&15)][ks*32 + (lane>>4)*8 + j] )
__global__ void prep_all(const float* __restrict__ W, const float* __restrict__ embs,
                         unsigned short* __restrict__ wfrag, unsigned* __restrict__ f8tab,
                         int total_ints) {
    const int b = blockIdx.x;
    if (b < 16) {
        const int t = b * 256 + threadIdx.x;          // 0..4095
        const int lane = t & 63;
        const int ks = (t >> 6) & 7;
        const int nt = t >> 9;
        const int n  = nt * 16 + (lane & 15);
        const int k0 = ks * 32 + (lane >> 4) * 8;
        const float* src = W + (size_t)n * TWO_D + k0;
        const float4 a = *reinterpret_cast<const float4*>(src);
        const float4 c = *reinterpret_cast<const float4*>(src + 4);
        ushort4 lo = { f2bf(a.x), f2bf(a.y), f2bf(a.z), f2bf(a.w) };
        ushort4 hi = { f2bf(c.x), f2bf(c.y), f2bf(c.z), f2bf(c.w) };
        unsigned short* dst = wfrag + (size_t)t * 8;
        *reinterpret_cast<ushort4*>(dst)     = lo;
        *reinterpret_cast<ushort4*>(dst + 4) = hi;
    } else {
        // fp8 e4m3 table: one int = 4 fp8 elems, from one float4 of embs
        int i = (b - 16) * 256 + threadIdx.x;
        const int stride = (gridDim.x - 16) * 256;
        for (; i < total_ints; i += stride) {
            const float4 v = reinterpret_cast<const float4*>(embs)[i];
            int p = 0;
            p = __builtin_amdgcn_cvt_pk_fp8_f32(v.x, v.y, p, false);
            p = __builtin_amdgcn_cvt_pk_fp8_f32(v.z, v.w, p, true);
            f8tab[i] = (unsigned)p;
        }
    }
}

template <int USE_F8>
__global__ __launch_bounds__(512, 8)
void sage_fused(const int* __restrict__ nodes,
                const float* __restrict__ embs,
                const unsigned* __restrict__ f8tab,
                const int* __restrict__ neigh,
                const unsigned short* __restrict__ wfrag,
                float* __restrict__ out,
                int n_nodes)
{
    __shared__ unsigned short comb[BM * LSTR];   // bf16 combined; reused as fp32 out staging
    __shared__ int sidx[BM];
    __shared__ int nb[BM * K_NEIGH];

    const int tid = threadIdx.x;
    const int block_n0 = blockIdx.x * BM;
    const int nvalid = min(BM, n_nodes - block_n0);   // 16 for all blocks (50000%16==0)

    // ---------- Phase 0: stage indices ----------
    if (tid < BM)
        sidx[tid] = (tid < nvalid) ? nodes[block_n0 + tid] : 0;
    if (tid < BM * K_NEIGH)
        nb[tid] = (tid < nvalid * K_NEIGH) ? neigh[(size_t)block_n0 * K_NEIGH + tid] : 0;
    __syncthreads();

    // ---------- Phase 1: gather. 32 lanes/node; self fp32 (16 B/lane), neigh fp8 (4 B/lane) --
    {
        const int nloc = tid >> 5;        // 0..15
        const int l = tid & 31;           // elem range [4l, 4l+4)
        unsigned short* row = &comb[nloc * LSTR];
        if (nloc < nvalid) {
            const int* nptr = &nb[nloc * K_NEIGH];
            // self: fp32 direct -> bf16 cols [0,128)
            const float4 sv = *reinterpret_cast<const float4*>(
                embs + (size_t)sidx[nloc] * IN_DIM + 4 * l);
            ushort4 t4 = { f2bf(sv.x), f2bf(sv.y), f2bf(sv.z), f2bf(sv.w) };
            *reinterpret_cast<ushort4*>(row + 4 * l) = t4;

            float ax[4] = {0.f, 0.f, 0.f, 0.f};
            if (USE_F8) {
                unsigned v[K_NEIGH];
                #pragma unroll
                for (int k = 0; k < K_NEIGH; ++k)
                    v[k] = f8tab[(size_t)nptr[k] * (IN_DIM / 4) + l];
                #pragma unroll
                for (int k = 0; k < K_NEIGH; ++k) {
                    const f32x2 lo = __builtin_amdgcn_cvt_pk_f32_fp8((int)v[k], false);
                    const f32x2 hi = __builtin_amdgcn_cvt_pk_f32_fp8((int)v[k], true);
                    ax[0] += lo[0]; ax[1] += lo[1]; ax[2] += hi[0]; ax[3] += hi[1];
                }
            } else {
                #pragma unroll
                for (int b2 = 0; b2 < 2; ++b2) {
                    float4 v[8];
                    #pragma unroll
                    for (int k = 0; k < 8; ++k)
                        v[k] = *reinterpret_cast<const float4*>(
                            embs + (size_t)nptr[b2 * 8 + k] * IN_DIM + 4 * l);
                    #pragma unroll
                    for (int k = 0; k < 8; ++k) {
                        ax[0] += v[k].x; ax[1] += v[k].y; ax[2] += v[k].z; ax[3] += v[k].w;
                    }
                }
            }
            u16x4 m4;
            #pragma unroll
            for (int j = 0; j < 4; ++j) m4[j] = f2bf(ax[j] * 0.0625f);
            *reinterpret_cast<u16x4*>(row + IN_DIM + 4 * l) = m4;
        } else {
            u16x4 z = { 0, 0, 0, 0 };
            *reinterpret_cast<u16x4*>(row + 4 * l) = z;
            *reinterpret_cast<u16x4*>(row + IN_DIM + 4 * l) = z;
        }
    }
    __syncthreads();

    // ---------- Phase 2: MFMA GEMM — 8 waves, wave w handles n-tile w, 8 k-steps ----------
    const int wave = tid >> 6;            // 0..7
    const int lane = tid & 63;
    const int row16 = lane & 15;
    const int hi    = lane >> 4;          // 0..3 -> k-base hi*8

    f32x4 acc = {0, 0, 0, 0};
    {
        const unsigned short* arow = &comb[row16 * LSTR + hi * 8];
        const unsigned short* bbase = wfrag + ((size_t)wave * 8 * 64 + (size_t)lane) * 8;
        #pragma unroll
        for (int ks = 0; ks < 8; ++ks) {
            const bf16x8 a = *reinterpret_cast<const bf16x8*>(arow + ks * 32);
            const bf16x8 b = *reinterpret_cast<const bf16x8*>(bbase + (size_t)ks * 64 * 8);
            acc = __builtin_amdgcn_mfma_f32_16x16x32_bf16(a, b, acc, 0, 0, 0);
        }
    }
    __syncthreads();   // comb A-reads done

    // ---------- Phase 3: stage relu(acc) in LDS [16][132], coalesced float4 stores ----------
    {
        float* otile = reinterpret_cast<float*>(comb);
        const int ncol = wave * 16 + row16;
        #pragma unroll
        for (int r = 0; r < 4; ++r)
            otile[(hi * 4 + r) * 132 + ncol] = fmaxf(acc[r], 0.f);
        __syncthreads();

        const int rrow = tid >> 5;        // 0..15
        const int seg  = tid & 31;        // 4 floats each
        if (rrow < nvalid) {
            *reinterpret_cast<float4*>(out + (size_t)(block_n0 + rrow) * OUT_DIM + seg * 4) =
                *reinterpret_cast<const float4*>(otile + rrow * 132 + seg * 4);
        }
    }
}

extern "C" void kernel_launch(void* const* d_in, const int* in_sizes, int n_in,
                              void* d_out, int out_size, void* d_ws, size_t ws_size,
                              hipStream_t stream) {
    const int*   nodes = (const int*)d_in[0];
    const float* embs  = (const float*)d_in[1];
    const int*   neigh = (const int*)d_in[2];
    const float* W     = (const float*)d_in[3];
    float* out = (float*)d_out;

    const int n_nodes = in_sizes[0];                       // 50000
    const int n_unique = in_sizes[1] / IN_DIM;             // 100000
    const size_t f8tab_bytes = (size_t)n_unique * IN_DIM;  // 12.8 MB (1 B/elem)
    const size_t wfrag_bytes = 8 * 8 * 64 * 8 * 2;         // 64 KiB
    const bool use_f8 = ws_size >= f8tab_bytes + wfrag_bytes;

    unsigned char* base = (unsigned char*)d_ws;
    unsigned* f8tab = (unsigned*)base;
    unsigned short* wfrag = (unsigned short*)(use_f8 ? base + f8tab_bytes : base);

    const int grid = (n_nodes + BM - 1) / BM;              // 3125

    if (use_f8) {
        const int total_ints = (int)(f8tab_bytes / 4);     // 3.2M
        prep_all<<<16 + 2048, 256, 0, stream>>>(W, embs, wfrag, f8tab, total_ints);
        sage_fused<1><<<grid, 512, 0, stream>>>(nodes, embs, f8tab, neigh, wfrag, out, n_nodes);
    } else {
        prep_all<<<16, 256, 0, stream>>>(W, embs, wfrag, f8tab, 0);
        sage_fused<0><<<grid, 512, 0, stream>>>(nodes, embs, f8tab, neigh, wfrag, out, n_nodes);
    }
}